// Round 3
// baseline (2489.511 us; speedup 1.0000x reference)
//
#include <hip/hip_runtime.h>
#include <hip/hip_bf16.h>

typedef __attribute__((ext_vector_type(8))) short short8;
typedef __attribute__((ext_vector_type(4))) float f32x4;
typedef __attribute__((ext_vector_type(2))) __fp16 fp16x2;
typedef __attribute__((ext_vector_type(8))) _Float16 half8;

#define SEQ 40
#define IN_DIM 24
#define NKER 36
#define ENC 128
#define HID 64
#define NSTEPS 50
#define BTOT 65536

// ---- ws float-element offsets ----
#define WS_FLAG 0
#define WS_DT   1
#define WS_CW   16        // [36][3][24] f32
#define WS_CB   2608      // [36]
#define WS_E1B  2644      // [128]
#define WS_B1   2772      // [64]  ode1_b
#define WS_CZ   2836      // [64]  W1*b2
#define WS_CB2  2900      // [32]  T*reg1*b2 + reg1_b
#define WS_R2W  2932      // [32]
#define WS_R2B  2964      // [1]
#define WS_EBZ  2976      // [64]  W1*enc2_b
#define WS_PB   3040      // [32]  reg1*enc2_b
// enc1 weights in MFMA B-fragment order, k' = s*40 + o (o padded to 40), K=1600
#define WS_BH   4096      // 204800 ushorts (hi)
#define WS_BL   106496    // 204800 ushorts (lo)
#define WS_MZH  221184    // [64][64] bf16 hi (2048 f)
#define WS_MZL  223232    // [64][64] bf16 lo
#define WS_QH   225280    // [32][64] bf16 hi (1024 f)
#define WS_QL   226304    // [32][64] bf16 lo
// folded enc2 weights [96][128] as f16 MFMA B-frags: [nt:6][kc:4][lane:64][j:8]
#define WS_EPWH 227328    // 12288 ushorts = 6144 f (f16 hi)
#define WS_EPWL 233472    // 12288 ushorts = 6144 f (f16 lo * 2048)
#define WS_ZP0  262144    // [B][96] f32: z0[64] + p0[32] per row

__device__ __forceinline__ unsigned short f2bf(float f){   // RNE
  union { float f; unsigned int u; } v; v.f = f;
  unsigned int r = (v.u + 0x7FFFu + ((v.u >> 16) & 1u)) >> 16;
  return (unsigned short)r;
}
__device__ __forceinline__ float bf2f(unsigned short s){
  union { unsigned int u; float f; } v; v.u = ((unsigned int)s) << 16; return v.f;
}
// packed bf16 pair (RNE) via hardware cvt
__device__ __forceinline__ unsigned int pk_bf16(float a, float b){
  unsigned int r;
  asm("v_cvt_pk_bf16_f32 %0, %1, %2" : "=v"(r) : "v"(a), "v"(b));
  return r;
}
// split pair into hi-pack + lo-pack (hi RNE, lo RNE) — 6 VALU ops
__device__ __forceinline__ void split_pair(float v0, float v1,
                                           unsigned int& h, unsigned int& lo){
  h = pk_bf16(v0, v1);
  union { unsigned int u; float f; } a, b;
  a.u = h << 16; b.u = h & 0xffff0000u;
  lo = pk_bf16(v0 - a.f, v1 - b.f);
}
// f16 helpers
__device__ __forceinline__ unsigned int pk_f16(float a, float b){
  fp16x2 h = __builtin_amdgcn_cvt_pkrtz(a, b);
  union { fp16x2 h; unsigned int u; } cv; cv.h = h; return cv.u;
}
__device__ __forceinline__ float f16lo(unsigned int u){
  union { unsigned short s; __fp16 h; } c; c.s = (unsigned short)(u & 0xffffu);
  return (float)c.h;
}
__device__ __forceinline__ float f16hi(unsigned int u){
  union { unsigned short s; __fp16 h; } c; c.s = (unsigned short)(u >> 16);
  return (float)c.h;
}
// tanh(x) = 1 - 2/(e^{2x}+1): 5 VALU ops
__device__ __forceinline__ float tanh5(float x){
  float e = __builtin_exp2f(x * 2.885390081777927f);   // e^{2x}
  float r = __builtin_amdgcn_rcpf(1.0f + e);
  return __builtin_fmaf(-2.0f, r, 1.0f);
}

// ---------------- detector ----------------
__global__ void k_detect(const void* __restrict__ x, const void* __restrict__ t_span,
                         float* __restrict__ ws){
  const unsigned int* xw = (const unsigned int*)x;
  int lane = threadIdx.x;
  int cnt = 0;
  #pragma unroll
  for (int i = 0; i < 16; i++){
    unsigned int w = xw[lane * 16 + i];
    unsigned int e = (w >> 7) & 0xFFu;
    cnt += (e >= 100u && e <= 140u) ? 1 : 0;
  }
  #pragma unroll
  for (int off = 32; off; off >>= 1) cnt += __shfl_down(cnt, off);
  if (lane == 0){
    int flag = (cnt >= 700) ? 1 : 0;
    float t0, t1;
    if (flag){
      t0 = __bfloat162float(((const __hip_bfloat16*)t_span)[0]);
      t1 = __bfloat162float(((const __hip_bfloat16*)t_span)[1]);
    } else {
      t0 = ((const float*)t_span)[0];
      t1 = ((const float*)t_span)[1];
    }
    ws[WS_FLAG] = (float)flag;
    ws[WS_DT] = (t1 - t0) / (float)NSTEPS;
  }
}

// ---------------- k0: weight convert + algebraic folds + frag packs ------
__global__ void k0_convert(const void* __restrict__ conv_w, const void* __restrict__ conv_b,
                           const void* __restrict__ enc1_w, const void* __restrict__ enc1_b,
                           const void* __restrict__ enc2_w, const void* __restrict__ enc2_b,
                           const void* __restrict__ ode1_w, const void* __restrict__ ode1_b,
                           const void* __restrict__ ode2_w, const void* __restrict__ ode2_b,
                           const void* __restrict__ reg1_w, const void* __restrict__ reg1_b,
                           const void* __restrict__ reg2_w, const void* __restrict__ reg2_b,
                           float* __restrict__ ws){
  const int flag = (int)ws[WS_FLAG];
  const float T = ws[WS_DT] * (float)NSTEPS;
  int t = blockIdx.x * 256 + threadIdx.x;
  int stride = gridDim.x * 256;

  #define RD(src, i) (flag ? __bfloat162float(((const __hip_bfloat16*)(src))[i]) \
                           : ((const float*)(src))[i])

  for (int i = t; i < NKER*72; i += stride){
    int o = i / 72, r = i % 72, dk = r / 24, c = r % 24;
    ws[WS_CW + i] = RD(conv_w, o*72 + c*3 + dk);
  }
  for (int i = t; i < NKER; i += stride) ws[WS_CB + i] = RD(conv_b, i);
  for (int i = t; i < ENC; i += stride) ws[WS_E1B + i] = RD(enc1_b, i);

  // enc1 B-fragments (split hi/lo bf16), k' = s*40 + o  (o in [36,40) -> 0)
  {
    unsigned short* bh = (unsigned short*)(ws + WS_BH);
    unsigned short* bl = (unsigned short*)(ws + WS_BL);
    for (int i = t; i < 8*50*64*8; i += stride){
      int j = i & 7, l = (i >> 3) & 63;
      int rem = i >> 9, ks = rem % 50, nt = rem / 50;
      int n = nt*16 + (l & 15);
      int kk = ks*32 + (l >> 4)*8 + j;
      int s = kk / 40, o = kk % 40;
      float v = (o < 36) ? RD(enc1_w, n*1440 + o*40 + s) : 0.0f;
      unsigned short h = f2bf(v);
      bh[i] = h; bl[i] = f2bf(v - bf2f(h));
    }
  }

  // folded enc2 [96][128] = [W1;reg1]*enc2_w, f16 B-frags, lo scaled x2048
  {
    unsigned short* eph = (unsigned short*)(ws + WS_EPWH);
    unsigned short* epl = (unsigned short*)(ws + WS_EPWL);
    for (int i = t; i < 6*4*64*8; i += stride){
      int j = i & 7, l = (i >> 3) & 63, kc = (i >> 9) & 3, nt = i >> 11;
      int n = nt*16 + (l & 15);
      int k = kc*32 + (l >> 4)*8 + j;
      float acc = 0.f;
      if (n < 64){
        for (int h = 0; h < 64; h++) acc += RD(ode1_w, n*64+h) * RD(enc2_w, h*128+k);
      } else {
        int p = n - 64;
        for (int h = 0; h < 64; h++) acc += RD(reg1_w, p*64+h) * RD(enc2_w, h*128+k);
      }
      unsigned int hp = pk_f16(acc, 0.f);
      float hf = f16lo(hp);
      unsigned int lp = pk_f16((acc - hf) * 2048.0f, 0.f);
      eph[i] = (unsigned short)(hp & 0xffffu);
      epl[i] = (unsigned short)(lp & 0xffffu);
    }
  }

  for (int i = t; i < 64; i += stride){
    float acc = 0.f;
    for (int h = 0; h < 64; h++) acc += RD(ode1_w, i*64+h) * RD(enc2_b, h);
    ws[WS_EBZ + i] = acc;
    float acc2 = 0.f;
    for (int h = 0; h < 64; h++) acc2 += RD(ode1_w, i*64+h) * RD(ode2_b, h);
    ws[WS_CZ + i] = acc2;
    ws[WS_B1 + i] = RD(ode1_b, i);
  }
  for (int i = t; i < 32; i += stride){
    float acc = 0.f;
    for (int h = 0; h < 64; h++) acc += RD(reg1_w, i*64+h) * RD(enc2_b, h);
    ws[WS_PB + i] = acc;
    float acc2 = 0.f;
    for (int h = 0; h < 64; h++) acc2 += RD(reg1_w, i*64+h) * RD(ode2_b, h);
    ws[WS_CB2 + i] = T * acc2 + RD(reg1_b, i);
    ws[WS_R2W + i] = RD(reg2_w, i);
  }
  if (t == 0) ws[WS_R2B] = RD(reg2_b, 0);

  // Mz = W1*W2 [64][64], split hi/lo bf16
  unsigned short* mzh = (unsigned short*)(ws + WS_MZH);
  unsigned short* mzl = (unsigned short*)(ws + WS_MZL);
  for (int i = t; i < 64*64; i += stride){
    int a = i >> 6, b = i & 63;
    float acc = 0.f;
    for (int h = 0; h < 64; h++) acc += RD(ode1_w, a*64+h) * RD(ode2_w, h*64+b);
    unsigned short hi = f2bf(acc);
    mzh[i] = hi; mzl[i] = f2bf(acc - bf2f(hi));
  }
  // Q = reg1*W2 [32][64], split hi/lo bf16
  unsigned short* qh = (unsigned short*)(ws + WS_QH);
  unsigned short* ql = (unsigned short*)(ws + WS_QL);
  for (int i = t; i < 32*64; i += stride){
    int p = i >> 6, b = i & 63;
    float acc = 0.f;
    for (int h = 0; h < 64; h++) acc += RD(reg1_w, p*64+h) * RD(ode2_w, h*64+b);
    unsigned short hi = f2bf(acc);
    qh[i] = hi; ql[i] = f2bf(acc - bf2f(hi));
  }
  #undef RD
}

// ---------------- k1: conv+silu -> MFMA enc1 -> MFMA folded enc2 ----------
// 1024 blocks x 256 thr (4 waves), 64 rows/block.
__launch_bounds__(256, 4)
__global__ void k1_encoder(const void* __restrict__ x,
                           const float* __restrict__ ws,
                           float* __restrict__ zp0){
  __shared__ float lds[10240];                       // 40 KB: Ahi/Alo, later e1[64][132]
  unsigned short* Ahi = (unsigned short*)lds;        // [64][160] ushort
  unsigned short* Alo = Ahi + 64*160;
  const int flag = (int)ws[WS_FLAG];
  const int t = threadIdx.x;
  const int lane = t & 63;
  const int gu = __builtin_amdgcn_readfirstlane(t >> 6);   // wave id, SGPR
  const int wm = gu >> 1, wn = gu & 1;
  const int l15 = lane & 15, q = lane >> 4;
  const int r = lane;                                // conv row 0..63
  const long rowbase = (long)blockIdx.x * 64;

  f32x4 acc[2][4];
  #pragma unroll
  for (int mt = 0; mt < 2; mt++)
    #pragma unroll
    for (int nt = 0; nt < 4; nt++)
      acc[mt][nt] = (f32x4){0.f, 0.f, 0.f, 0.f};

  const unsigned short* BH = (const unsigned short*)(ws + WS_BH);
  const unsigned short* BL = (const unsigned short*)(ws + WS_BL);
  const float* CW = ws + WS_CW;
  const float* CB = ws + WS_CB;

  float xc[24];
  auto loadcol = [&](int col){
    if (col >= 0 && col < SEQ){
      if (flag){
        const __hip_bfloat16* xp = (const __hip_bfloat16*)x + (rowbase + r)*(SEQ*IN_DIM) + col*IN_DIM;
        const uint4* px = (const uint4*)xp;
        #pragma unroll
        for (int w8 = 0; w8 < 3; w8++){
          uint4 u = px[w8];
          unsigned int uu[4] = {u.x, u.y, u.z, u.w};
          #pragma unroll
          for (int e = 0; e < 4; e++){
            union { unsigned int i; float f; } lo, hi;
            lo.i = uu[e] << 16; hi.i = uu[e] & 0xffff0000u;
            xc[w8*8 + 2*e] = lo.f; xc[w8*8 + 2*e + 1] = hi.f;
          }
        }
      } else {
        const float* xp = (const float*)x + (rowbase + r)*(SEQ*IN_DIM) + col*IN_DIM;
        #pragma unroll
        for (int w4 = 0; w4 < 6; w4++){
          float4 v = ((const float4*)xp)[w4];
          xc[4*w4] = v.x; xc[4*w4+1] = v.y; xc[4*w4+2] = v.z; xc[4*w4+3] = v.w;
        }
      }
    } else {
      #pragma unroll
      for (int cc = 0; cc < 24; cc++) xc[cc] = 0.f;
    }
  };

  auto swzb = [](int blk, int rw){ return blk ^ ((blk < 16) ? (rw & 7) : (rw & 3)); };

  #pragma unroll 1
  for (int c = 0; c < 10; c++){
    __syncthreads();   // prev chunk's MFMA reads done (cross-wave)
    // ---- conv phase: row r, s-column = c*4 + gu ----
    {
      const int s = c*4 + gu;
      float accv[36];
      #pragma unroll
      for (int o = 0; o < 36; o++) accv[o] = CB[o];
      #pragma unroll 1
      for (int dk = 0; dk < 3; dk++){
        loadcol(s - 1 + dk);
        const float* wdk = CW + dk*24;
        #pragma unroll
        for (int o = 0; o < 36; o++){
          const float* wo = wdk + o*72;
          float a = accv[o];
          #pragma unroll
          for (int ci = 0; ci < 24; ci++) a += wo[ci] * xc[ci];
          accv[o] = a;
        }
      }
      const int kb0 = gu * 40;
      #pragma unroll
      for (int o = 0; o < 40; o += 2){
        unsigned int hpack, lpack;
        if (o < 36){
          float v0 = accv[o];     v0 = v0 * __builtin_amdgcn_rcpf(1.0f + __expf(-v0));
          float v1 = accv[o + 1]; v1 = v1 * __builtin_amdgcn_rcpf(1.0f + __expf(-v1));
          split_pair(v0, v1, hpack, lpack);
        } else { hpack = 0u; lpack = 0u; }
        int k = kb0 + o;
        int idx = r*160 + (swzb(k >> 3, r) << 3) + (k & 7);
        *(unsigned int*)(Ahi + idx) = hpack;
        *(unsigned int*)(Alo + idx) = lpack;
      }
    }
    __syncthreads();
    // ---- MFMA phase: 5 k-steps of 32 ----
    #pragma unroll
    for (int ksl = 0; ksl < 5; ksl++){
      const int ks = c*5 + ksl;
      short8 ah[2], al[2];
      #pragma unroll
      for (int mt = 0; mt < 2; mt++){
        int rr = wm*32 + mt*16 + l15;
        int kb = ksl*4 + q;
        int idx = rr*160 + (swzb(kb, rr) << 3);
        ah[mt] = *(const short8*)(Ahi + idx);
        al[mt] = *(const short8*)(Alo + idx);
      }
      #pragma unroll
      for (int nt = 0; nt < 4; nt++){
        int fo = (((wn*4 + nt)*50 + ks)*64 + lane) << 3;
        short8 bh = *(const short8*)(BH + fo);
        short8 bl = *(const short8*)(BL + fo);
        #pragma unroll
        for (int mt = 0; mt < 2; mt++){
          acc[mt][nt] = __builtin_amdgcn_mfma_f32_16x16x32_bf16(ah[mt], bh, acc[mt][nt], 0, 0, 0);
          acc[mt][nt] = __builtin_amdgcn_mfma_f32_16x16x32_bf16(al[mt], bh, acc[mt][nt], 0, 0, 0);
          acc[mt][nt] = __builtin_amdgcn_mfma_f32_16x16x32_bf16(ah[mt], bl, acc[mt][nt], 0, 0, 0);
        }
      }
    }
  }

  // ---- e1 = relu(acc + e1_b) -> LDS [64][132] f32 (16B-aligned rows) ----
  __syncthreads();
  float* e1buf = lds;
  #pragma unroll
  for (int mt = 0; mt < 2; mt++){
    #pragma unroll
    for (int nt = 0; nt < 4; nt++){
      int col = wn*64 + nt*16 + l15;
      float bias = ws[WS_E1B + col];
      #pragma unroll
      for (int r2 = 0; r2 < 4; r2++){
        int row = wm*32 + mt*16 + q*4 + r2;
        float v = acc[mt][nt][r2] + bias;
        e1buf[row*132 + col] = v > 0.0f ? v : 0.0f;
      }
    }
  }
  __syncthreads();

  // ---- folded enc2 via f16-split MFMA: zp = EPW . e1 + bias ----
  // wave gu handles batch rows gu*16..gu*16+15 (A: m=l15=batch, k over q*8+j)
  {
    half8 eh[4], el[4];
    const int myrow = gu*16 + l15;
    #pragma unroll
    for (int kc = 0; kc < 4; kc++){
      const float* ep = e1buf + myrow*132 + kc*32 + q*8;
      f32x4 va = *(const f32x4*)(ep);
      f32x4 vb = *(const f32x4*)(ep + 4);
      float v[8] = {va[0],va[1],va[2],va[3],vb[0],vb[1],vb[2],vb[3]};
      union { unsigned int u[4]; half8 h8; } H, L;
      #pragma unroll
      for (int p = 0; p < 4; p++){
        unsigned int h = pk_f16(v[2*p], v[2*p+1]);
        float r0 = v[2*p]   - f16lo(h);
        float r1 = v[2*p+1] - f16hi(h);
        H.u[p] = h;
        L.u[p] = pk_f16(r0, r1);
      }
      eh[kc] = H.h8; el[kc] = L.h8;
    }
    const unsigned short* EPH = (const unsigned short*)(ws + WS_EPWH);
    const unsigned short* EPL = (const unsigned short*)(ws + WS_EPWL);
    #pragma unroll 1
    for (int nt = 0; nt < 6; nt++){
      f32x4 c1 = (f32x4){0.f,0.f,0.f,0.f};
      f32x4 c2 = (f32x4){0.f,0.f,0.f,0.f};
      #pragma unroll
      for (int kc = 0; kc < 4; kc++){
        int fo = (((nt*4 + kc)*64 + lane)) << 3;
        half8 bh = *(const half8*)(EPH + fo);
        half8 bl = *(const half8*)(EPL + fo);
        c1 = __builtin_amdgcn_mfma_f32_16x16x32_f16(eh[kc], bh, c1, 0, 0, 0);
        c1 = __builtin_amdgcn_mfma_f32_16x16x32_f16(el[kc], bh, c1, 0, 0, 0);
        c2 = __builtin_amdgcn_mfma_f32_16x16x32_f16(eh[kc], bl, c2, 0, 0, 0);
      }
      float bias = (nt < 4) ? ws[WS_EBZ + nt*16 + l15] : ws[WS_PB + (nt-4)*16 + l15];
      #pragma unroll
      for (int rr = 0; rr < 4; rr++){
        zp0[(long)(rowbase + gu*16 + q*4 + rr)*96 + nt*16 + l15]
            = c1[rr] + c2[rr]*(1.0f/2048.0f) + bias;
      }
    }
  }
}

// ---------------- k2: 50 dopri5 steps (operand-swapped, barrier-free) -----
// 1 wave/block, 16 batch rows. D = Mz·u^T: A = Mz (static regs), B = u.
// State layout: batch = lane&15, hid dim = mt*16 + q*4 + r (in regs).
// C-layout of D == this layout, so only a tiny LDS bounce re-shapes u into
// B-frags (8x ds_write_b64 + 4x ds_read_b128, XOR-swizzled; same-wave DS is
// in-order => no barriers).
__launch_bounds__(64, 2)
__global__ void k2_ode(const float* __restrict__ ws,
                       const float* __restrict__ zp0,
                       float* __restrict__ out){
  __shared__ unsigned int scr[1152];        // Uh[576] + Ul[576] (16 x 36 u32 each)
  unsigned int* Uh = scr;
  unsigned int* Ul = scr + 576;
  const int tid = threadIdx.x;
  const int l15 = tid & 15, q = tid >> 4;
  const int hswz = (l15 & 1) << 4;          // bank swizzle: XOR slot bit4
  const int rowbase = blockIdx.x * 16;

  // Mz A-frags: value = Mz[mt*16+l15][kc*32+q*8+j]
  short8 Ah[4][2], Al[4][2];
  {
    const short8* pmh = (const short8*)(ws + WS_MZH);
    const short8* pml = (const short8*)(ws + WS_MZL);
    #pragma unroll
    for (int mt = 0; mt < 4; mt++)
      #pragma unroll
      for (int kc = 0; kc < 2; kc++){
        int idx = (mt*16 + l15)*8 + kc*4 + q;
        Ah[mt][kc] = pmh[idx];
        Al[mt][kc] = pml[idx];
      }
  }
  float b1a[16], cza[16];
  #pragma unroll
  for (int mt = 0; mt < 4; mt++){
    f32x4 b  = *(const f32x4*)(ws + WS_B1 + mt*16 + q*4);
    f32x4 cz = *(const f32x4*)(ws + WS_CZ + mt*16 + q*4);
    #pragma unroll
    for (int rr = 0; rr < 4; rr++){ b1a[mt*4+rr] = b[rr]; cza[mt*4+rr] = cz[rr]; }
  }
  const float dt = ws[WS_DT];

  float z[16], s[16];
  #pragma unroll
  for (int mt = 0; mt < 4; mt++){
    f32x4 v = *(const f32x4*)(zp0 + (long)(rowbase + l15)*96 + mt*16 + q*4);
    #pragma unroll
    for (int rr = 0; rr < 4; rr++){ z[mt*4+rr] = v[rr]; s[mt*4+rr] = 0.0f; }
  }

  const int wbase = l15*36;

  auto feval = [&](const float* in, float* g, float w){
    float u[16];
    #pragma unroll
    for (int i = 0; i < 16; i++) u[i] = tanh5(in[i] + b1a[i]);
    if (w != 0.0f){
      #pragma unroll
      for (int i = 0; i < 16; i++) s[i] += w * u[i];
    }
    #pragma unroll
    for (int mt = 0; mt < 4; mt++){
      unsigned int h01, lo01, h23, lo23;
      split_pair(u[mt*4+0], u[mt*4+1], h01, lo01);
      split_pair(u[mt*4+2], u[mt*4+3], h23, lo23);
      int slot = wbase + ((8*mt + 2*q) ^ hswz);
      *(uint2*)(Uh + slot) = make_uint2(h01, h23);
      *(uint2*)(Ul + slot) = make_uint2(lo01, lo23);
    }
    f32x4 c[4];
    #pragma unroll
    for (int mt = 0; mt < 4; mt++) c[mt] = (f32x4){0.f,0.f,0.f,0.f};
    #pragma unroll
    for (int kc = 0; kc < 2; kc++){
      int rb = wbase + ((16*kc + 4*q) ^ hswz);
      short8 bh = *(const short8*)(Uh + rb);
      short8 bl = *(const short8*)(Ul + rb);
      #pragma unroll
      for (int mt = 0; mt < 4; mt++){
        c[mt] = __builtin_amdgcn_mfma_f32_16x16x32_bf16(Ah[mt][kc], bh, c[mt], 0, 0, 0);
        c[mt] = __builtin_amdgcn_mfma_f32_16x16x32_bf16(Al[mt][kc], bh, c[mt], 0, 0, 0);
        c[mt] = __builtin_amdgcn_mfma_f32_16x16x32_bf16(Ah[mt][kc], bl, c[mt], 0, 0, 0);
      }
    }
    #pragma unroll
    for (int i = 0; i < 16; i++) g[i] = c[i>>2][i&3] + cza[i];
  };

  // tableau (g2 folded into A = c31*g1 + c32*g2; g6 reuses A)
  const float c21 = dt * 0.2f;
  const float c31 = dt * (3.0f/40.0f),  c32 = dt * (9.0f/40.0f);
  const float c43 = dt * (32.0f/9.0f);
  const float c53 = dt * (64448.0f/6561.0f), c54 = dt * (-212.0f/729.0f);
  const float c63 = dt * (46732.0f/5247.0f), c64 = dt * (49.0f/176.0f),
              c65 = dt * (-5103.0f/18656.0f);
  const float r42 = -448.0f/27.0f,          c41p = dt * (20.0f/9.0f);
  const float r52 = -1014400.0f/19683.0f,   c51p = dt * (134196.0f/19683.0f);
  const float r62 = -14200.0f/297.0f,       c61p = dt * (9017.0f/3168.0f + 42600.0f/11880.0f);
  const float d1 = dt * (35.0f/384.0f), d3 = dt * (500.0f/1113.0f), d4 = dt * (125.0f/192.0f),
              d5 = dt * (-2187.0f/6784.0f), d6 = dt * (11.0f/84.0f);

  float g1[16], A[16], g3[16], g4[16], g5[16], yt[16];

  #pragma unroll 1
  for (int st = 0; st < NSTEPS; st++){
    feval(z, g1, d1);
    #pragma unroll
    for (int i = 0; i < 16; i++) yt[i] = z[i] + c21*g1[i];
    feval(yt, A, 0.0f);
    #pragma unroll
    for (int i = 0; i < 16; i++){
      A[i]  = c31*g1[i] + c32*A[i];
      yt[i] = z[i] + A[i];
    }
    feval(yt, g3, d3);
    #pragma unroll
    for (int i = 0; i < 16; i++) yt[i] = z[i] + r42*A[i] + c41p*g1[i] + c43*g3[i];
    feval(yt, g4, d4);
    #pragma unroll
    for (int i = 0; i < 16; i++) yt[i] = z[i] + r52*A[i] + c51p*g1[i] + c53*g3[i] + c54*g4[i];
    feval(yt, g5, d5);
    #pragma unroll
    for (int i = 0; i < 16; i++) yt[i] = z[i] + r62*A[i] + c61p*g1[i] + c63*g3[i] + c64*g4[i] + c65*g5[i];
    feval(yt, A, d6);   // A := g6
    #pragma unroll
    for (int i = 0; i < 16; i++) z[i] += d1*g1[i] + d3*g3[i] + d4*g4[i] + d5*g5[i] + d6*A[i];
  }

  // ---- regressor: r = relu(p0 + Q*s + cb); out = reg2.r + r2b ----
  {
    #pragma unroll
    for (int mt = 0; mt < 4; mt++){
      unsigned int h01, lo01, h23, lo23;
      split_pair(s[mt*4+0], s[mt*4+1], h01, lo01);
      split_pair(s[mt*4+2], s[mt*4+3], h23, lo23);
      int slot = wbase + ((8*mt + 2*q) ^ hswz);
      *(uint2*)(Uh + slot) = make_uint2(h01, h23);
      *(uint2*)(Ul + slot) = make_uint2(lo01, lo23);
    }
    const short8* pqh = (const short8*)(ws + WS_QH);
    const short8* pql = (const short8*)(ws + WS_QL);
    f32x4 cv[2];
    cv[0] = (f32x4){0.f,0.f,0.f,0.f};
    cv[1] = (f32x4){0.f,0.f,0.f,0.f};
    #pragma unroll
    for (int kc = 0; kc < 2; kc++){
      int rb = wbase + ((16*kc + 4*q) ^ hswz);
      short8 bh = *(const short8*)(Uh + rb);
      short8 bl = *(const short8*)(Ul + rb);
      #pragma unroll
      for (int mt2 = 0; mt2 < 2; mt2++){
        int idx = (mt2*16 + l15)*8 + kc*4 + q;
        short8 qh = pqh[idx];
        short8 qlf = pql[idx];
        cv[mt2] = __builtin_amdgcn_mfma_f32_16x16x32_bf16(qh,  bh, cv[mt2], 0, 0, 0);
        cv[mt2] = __builtin_amdgcn_mfma_f32_16x16x32_bf16(qlf, bh, cv[mt2], 0, 0, 0);
        cv[mt2] = __builtin_amdgcn_mfma_f32_16x16x32_bf16(qh,  bl, cv[mt2], 0, 0, 0);
      }
    }
    float part = 0.f;
    #pragma unroll
    for (int mt2 = 0; mt2 < 2; mt2++){
      f32x4 cb = *(const f32x4*)(ws + WS_CB2 + mt2*16 + q*4);
      f32x4 p0 = *(const f32x4*)(zp0 + (long)(rowbase + l15)*96 + 64 + mt2*16 + q*4);
      f32x4 w2 = *(const f32x4*)(ws + WS_R2W + mt2*16 + q*4);
      #pragma unroll
      for (int rr = 0; rr < 4; rr++){
        float v = cv[mt2][rr] + cb[rr] + p0[rr];
        v = v > 0.0f ? v : 0.0f;
        part += w2[rr] * v;
      }
    }
    part += __shfl_xor(part, 16);
    part += __shfl_xor(part, 32);
    if (q == 0) out[rowbase + l15] = part + ws[WS_R2B];
  }
}

// ---------------------------------------------------------------------------
extern "C" void kernel_launch(void* const* d_in, const int* in_sizes, int n_in,
                              void* d_out, int out_size, void* d_ws, size_t ws_size,
                              hipStream_t stream){
  (void)in_sizes; (void)n_in; (void)out_size; (void)ws_size;
  float* ws = (float*)d_ws;

  k_detect<<<dim3(1), dim3(64), 0, stream>>>(d_in[0], d_in[1], ws);
  k0_convert<<<dim3(64), dim3(256), 0, stream>>>(
      d_in[2], d_in[3], d_in[4], d_in[5], d_in[6], d_in[7],
      d_in[8], d_in[9], d_in[10], d_in[11], d_in[12], d_in[13],
      d_in[14], d_in[15], ws);
  k1_encoder<<<dim3(BTOT/64), dim3(256), 0, stream>>>(d_in[0], ws, ws + WS_ZP0);
  k2_ode<<<dim3(BTOT/16), dim3(64), 0, stream>>>(ws, ws + WS_ZP0, (float*)d_out);
}

// Round 4
// 2327.198 us; speedup vs baseline: 1.0697x; 1.0697x over previous
//
#include <hip/hip_runtime.h>
#include <hip/hip_bf16.h>

typedef __attribute__((ext_vector_type(8))) short short8;
typedef __attribute__((ext_vector_type(4))) float f32x4;
typedef __attribute__((ext_vector_type(2))) __fp16 fp16x2;
typedef __attribute__((ext_vector_type(8))) _Float16 half8;

#define SEQ 40
#define IN_DIM 24
#define NKER 36
#define ENC 128
#define HID 64
#define NSTEPS 50
#define BTOT 65536

// ---- ws float-element offsets ----
#define WS_FLAG 0
#define WS_DT   1
#define WS_CW   16        // [36][3][24] f32
#define WS_CB   2608      // [36]
#define WS_E1B  2644      // [128]
#define WS_B1   2772      // [64]  ode1_b
#define WS_CZ   2836      // [64]  W1*b2
#define WS_CB2  2900      // [32]  T*reg1*b2 + reg1_b
#define WS_R2W  2932      // [32]
#define WS_R2B  2964      // [1]
#define WS_EBZ  2976      // [64]  W1*enc2_b
#define WS_PB   3040      // [32]  reg1*enc2_b
// enc1 weights in MFMA B-fragment order, k' = s*40 + o (o padded to 40), K=1600
#define WS_BH   4096      // 204800 ushorts (hi)
#define WS_BL   106496    // 204800 ushorts (lo)
#define WS_MZH  221184    // [64][64] bf16 hi (2048 f)
#define WS_MZL  223232    // [64][64] bf16 lo
#define WS_QH   225280    // [32][64] bf16 hi (1024 f)
#define WS_QL   226304    // [32][64] bf16 lo
// folded enc2 weights [96][128] as f16 MFMA B-frags: [nt:6][kc:4][lane:64][j:8]
#define WS_EPWH 227328    // 12288 ushorts = 6144 f (f16 hi)
#define WS_EPWL 233472    // 12288 ushorts = 6144 f (f16 lo * 2048)
#define WS_ZP0  262144    // [B][96] f32: z0[64] + p0[32] per row

__device__ __forceinline__ unsigned short f2bf(float f){   // RNE
  union { float f; unsigned int u; } v; v.f = f;
  unsigned int r = (v.u + 0x7FFFu + ((v.u >> 16) & 1u)) >> 16;
  return (unsigned short)r;
}
__device__ __forceinline__ float bf2f(unsigned short s){
  union { unsigned int u; float f; } v; v.u = ((unsigned int)s) << 16; return v.f;
}
// packed bf16 pair (RNE) via hardware cvt
__device__ __forceinline__ unsigned int pk_bf16(float a, float b){
  unsigned int r;
  asm("v_cvt_pk_bf16_f32 %0, %1, %2" : "=v"(r) : "v"(a), "v"(b));
  return r;
}
// split pair into hi-pack + lo-pack (hi RNE, lo RNE) — 6 VALU ops
__device__ __forceinline__ void split_pair(float v0, float v1,
                                           unsigned int& h, unsigned int& lo){
  h = pk_bf16(v0, v1);
  union { unsigned int u; float f; } a, b;
  a.u = h << 16; b.u = h & 0xffff0000u;
  lo = pk_bf16(v0 - a.f, v1 - b.f);
}
// f16 helpers
__device__ __forceinline__ unsigned int pk_f16(float a, float b){
  fp16x2 h = __builtin_amdgcn_cvt_pkrtz(a, b);
  union { fp16x2 h; unsigned int u; } cv; cv.h = h; return cv.u;
}
__device__ __forceinline__ float f16lo(unsigned int u){
  union { unsigned short s; __fp16 h; } c; c.s = (unsigned short)(u & 0xffffu);
  return (float)c.h;
}
__device__ __forceinline__ float f16hi(unsigned int u){
  union { unsigned short s; __fp16 h; } c; c.s = (unsigned short)(u >> 16);
  return (float)c.h;
}
// tanh(x) = 1 - 2/(e^{2x}+1): 5 VALU ops
__device__ __forceinline__ float tanh5(float x){
  float e = __builtin_exp2f(x * 2.885390081777927f);   // e^{2x}
  float r = __builtin_amdgcn_rcpf(1.0f + e);
  return __builtin_fmaf(-2.0f, r, 1.0f);
}

// ---------------- detector ----------------
__global__ void k_detect(const void* __restrict__ x, const void* __restrict__ t_span,
                         float* __restrict__ ws){
  const unsigned int* xw = (const unsigned int*)x;
  int lane = threadIdx.x;
  int cnt = 0;
  #pragma unroll
  for (int i = 0; i < 16; i++){
    unsigned int w = xw[lane * 16 + i];
    unsigned int e = (w >> 7) & 0xFFu;
    cnt += (e >= 100u && e <= 140u) ? 1 : 0;
  }
  #pragma unroll
  for (int off = 32; off; off >>= 1) cnt += __shfl_down(cnt, off);
  if (lane == 0){
    int flag = (cnt >= 700) ? 1 : 0;
    float t0, t1;
    if (flag){
      t0 = __bfloat162float(((const __hip_bfloat16*)t_span)[0]);
      t1 = __bfloat162float(((const __hip_bfloat16*)t_span)[1]);
    } else {
      t0 = ((const float*)t_span)[0];
      t1 = ((const float*)t_span)[1];
    }
    ws[WS_FLAG] = (float)flag;
    ws[WS_DT] = (t1 - t0) / (float)NSTEPS;
  }
}

// ---------------- k0: weight convert + algebraic folds + frag packs ------
__global__ void k0_convert(const void* __restrict__ conv_w, const void* __restrict__ conv_b,
                           const void* __restrict__ enc1_w, const void* __restrict__ enc1_b,
                           const void* __restrict__ enc2_w, const void* __restrict__ enc2_b,
                           const void* __restrict__ ode1_w, const void* __restrict__ ode1_b,
                           const void* __restrict__ ode2_w, const void* __restrict__ ode2_b,
                           const void* __restrict__ reg1_w, const void* __restrict__ reg1_b,
                           const void* __restrict__ reg2_w, const void* __restrict__ reg2_b,
                           float* __restrict__ ws){
  const int flag = (int)ws[WS_FLAG];
  const float T = ws[WS_DT] * (float)NSTEPS;
  int t = blockIdx.x * 256 + threadIdx.x;
  int stride = gridDim.x * 256;

  #define RD(src, i) (flag ? __bfloat162float(((const __hip_bfloat16*)(src))[i]) \
                           : ((const float*)(src))[i])

  for (int i = t; i < NKER*72; i += stride){
    int o = i / 72, r = i % 72, dk = r / 24, c = r % 24;
    ws[WS_CW + i] = RD(conv_w, o*72 + c*3 + dk);
  }
  for (int i = t; i < NKER; i += stride) ws[WS_CB + i] = RD(conv_b, i);
  for (int i = t; i < ENC; i += stride) ws[WS_E1B + i] = RD(enc1_b, i);

  // enc1 B-fragments (split hi/lo bf16), k' = s*40 + o  (o in [36,40) -> 0)
  {
    unsigned short* bh = (unsigned short*)(ws + WS_BH);
    unsigned short* bl = (unsigned short*)(ws + WS_BL);
    for (int i = t; i < 8*50*64*8; i += stride){
      int j = i & 7, l = (i >> 3) & 63;
      int rem = i >> 9, ks = rem % 50, nt = rem / 50;
      int n = nt*16 + (l & 15);
      int kk = ks*32 + (l >> 4)*8 + j;
      int s = kk / 40, o = kk % 40;
      float v = (o < 36) ? RD(enc1_w, n*1440 + o*40 + s) : 0.0f;
      unsigned short h = f2bf(v);
      bh[i] = h; bl[i] = f2bf(v - bf2f(h));
    }
  }

  // folded enc2 [96][128] = [W1;reg1]*enc2_w, f16 B-frags, lo scaled x2048
  {
    unsigned short* eph = (unsigned short*)(ws + WS_EPWH);
    unsigned short* epl = (unsigned short*)(ws + WS_EPWL);
    for (int i = t; i < 6*4*64*8; i += stride){
      int j = i & 7, l = (i >> 3) & 63, kc = (i >> 9) & 3, nt = i >> 11;
      int n = nt*16 + (l & 15);
      int k = kc*32 + (l >> 4)*8 + j;
      float acc = 0.f;
      if (n < 64){
        for (int h = 0; h < 64; h++) acc += RD(ode1_w, n*64+h) * RD(enc2_w, h*128+k);
      } else {
        int p = n - 64;
        for (int h = 0; h < 64; h++) acc += RD(reg1_w, p*64+h) * RD(enc2_w, h*128+k);
      }
      unsigned int hp = pk_f16(acc, 0.f);
      float hf = f16lo(hp);
      unsigned int lp = pk_f16((acc - hf) * 2048.0f, 0.f);
      eph[i] = (unsigned short)(hp & 0xffffu);
      epl[i] = (unsigned short)(lp & 0xffffu);
    }
  }

  for (int i = t; i < 64; i += stride){
    float acc = 0.f;
    for (int h = 0; h < 64; h++) acc += RD(ode1_w, i*64+h) * RD(enc2_b, h);
    ws[WS_EBZ + i] = acc;
    float acc2 = 0.f;
    for (int h = 0; h < 64; h++) acc2 += RD(ode1_w, i*64+h) * RD(ode2_b, h);
    ws[WS_CZ + i] = acc2;
    ws[WS_B1 + i] = RD(ode1_b, i);
  }
  for (int i = t; i < 32; i += stride){
    float acc = 0.f;
    for (int h = 0; h < 64; h++) acc += RD(reg1_w, i*64+h) * RD(enc2_b, h);
    ws[WS_PB + i] = acc;
    float acc2 = 0.f;
    for (int h = 0; h < 64; h++) acc2 += RD(reg1_w, i*64+h) * RD(ode2_b, h);
    ws[WS_CB2 + i] = T * acc2 + RD(reg1_b, i);
    ws[WS_R2W + i] = RD(reg2_w, i);
  }
  if (t == 0) ws[WS_R2B] = RD(reg2_b, 0);

  // Mz = W1*W2 [64][64], split hi/lo bf16
  unsigned short* mzh = (unsigned short*)(ws + WS_MZH);
  unsigned short* mzl = (unsigned short*)(ws + WS_MZL);
  for (int i = t; i < 64*64; i += stride){
    int a = i >> 6, b = i & 63;
    float acc = 0.f;
    for (int h = 0; h < 64; h++) acc += RD(ode1_w, a*64+h) * RD(ode2_w, h*64+b);
    unsigned short hi = f2bf(acc);
    mzh[i] = hi; mzl[i] = f2bf(acc - bf2f(hi));
  }
  // Q = reg1*W2 [32][64], split hi/lo bf16
  unsigned short* qh = (unsigned short*)(ws + WS_QH);
  unsigned short* ql = (unsigned short*)(ws + WS_QL);
  for (int i = t; i < 32*64; i += stride){
    int p = i >> 6, b = i & 63;
    float acc = 0.f;
    for (int h = 0; h < 64; h++) acc += RD(reg1_w, p*64+h) * RD(ode2_w, h*64+b);
    unsigned short hi = f2bf(acc);
    qh[i] = hi; ql[i] = f2bf(acc - bf2f(hi));
  }
  #undef RD
}

// ---------------- k1: conv+silu -> MFMA enc1 -> MFMA folded enc2 ----------
// 1024 blocks x 256 thr (4 waves), 64 rows/block.
__launch_bounds__(256, 4)
__global__ void k1_encoder(const void* __restrict__ x,
                           const float* __restrict__ ws,
                           float* __restrict__ zp0){
  __shared__ float lds[10240];                       // 40 KB: Ahi/Alo, later e1[64][132]
  unsigned short* Ahi = (unsigned short*)lds;        // [64][160] ushort
  unsigned short* Alo = Ahi + 64*160;
  const int flag = (int)ws[WS_FLAG];
  const int t = threadIdx.x;
  const int lane = t & 63;
  const int gu = __builtin_amdgcn_readfirstlane(t >> 6);   // wave id, SGPR
  const int wm = gu >> 1, wn = gu & 1;
  const int l15 = lane & 15, q = lane >> 4;
  const int r = lane;                                // conv row 0..63
  const long rowbase = (long)blockIdx.x * 64;

  f32x4 acc[2][4];
  #pragma unroll
  for (int mt = 0; mt < 2; mt++)
    #pragma unroll
    for (int nt = 0; nt < 4; nt++)
      acc[mt][nt] = (f32x4){0.f, 0.f, 0.f, 0.f};

  const unsigned short* BH = (const unsigned short*)(ws + WS_BH);
  const unsigned short* BL = (const unsigned short*)(ws + WS_BL);
  const float* CW = ws + WS_CW;
  const float* CB = ws + WS_CB;

  float xc[24];
  auto loadcol = [&](int col){
    if (col >= 0 && col < SEQ){
      if (flag){
        const __hip_bfloat16* xp = (const __hip_bfloat16*)x + (rowbase + r)*(SEQ*IN_DIM) + col*IN_DIM;
        const uint4* px = (const uint4*)xp;
        #pragma unroll
        for (int w8 = 0; w8 < 3; w8++){
          uint4 u = px[w8];
          unsigned int uu[4] = {u.x, u.y, u.z, u.w};
          #pragma unroll
          for (int e = 0; e < 4; e++){
            union { unsigned int i; float f; } lo, hi;
            lo.i = uu[e] << 16; hi.i = uu[e] & 0xffff0000u;
            xc[w8*8 + 2*e] = lo.f; xc[w8*8 + 2*e + 1] = hi.f;
          }
        }
      } else {
        const float* xp = (const float*)x + (rowbase + r)*(SEQ*IN_DIM) + col*IN_DIM;
        #pragma unroll
        for (int w4 = 0; w4 < 6; w4++){
          float4 v = ((const float4*)xp)[w4];
          xc[4*w4] = v.x; xc[4*w4+1] = v.y; xc[4*w4+2] = v.z; xc[4*w4+3] = v.w;
        }
      }
    } else {
      #pragma unroll
      for (int cc = 0; cc < 24; cc++) xc[cc] = 0.f;
    }
  };

  auto swzb = [](int blk, int rw){ return blk ^ ((blk < 16) ? (rw & 7) : (rw & 3)); };

  #pragma unroll 1
  for (int c = 0; c < 10; c++){
    __syncthreads();   // prev chunk's MFMA reads done (cross-wave)
    // ---- conv phase: row r, s-column = c*4 + gu ----
    {
      const int s = c*4 + gu;
      float accv[36];
      #pragma unroll
      for (int o = 0; o < 36; o++) accv[o] = CB[o];
      #pragma unroll 1
      for (int dk = 0; dk < 3; dk++){
        loadcol(s - 1 + dk);
        const float* wdk = CW + dk*24;
        #pragma unroll
        for (int o = 0; o < 36; o++){
          const float* wo = wdk + o*72;
          float a = accv[o];
          #pragma unroll
          for (int ci = 0; ci < 24; ci++) a += wo[ci] * xc[ci];
          accv[o] = a;
        }
      }
      const int kb0 = gu * 40;
      #pragma unroll
      for (int o = 0; o < 40; o += 2){
        unsigned int hpack, lpack;
        if (o < 36){
          float v0 = accv[o];     v0 = v0 * __builtin_amdgcn_rcpf(1.0f + __expf(-v0));
          float v1 = accv[o + 1]; v1 = v1 * __builtin_amdgcn_rcpf(1.0f + __expf(-v1));
          split_pair(v0, v1, hpack, lpack);
        } else { hpack = 0u; lpack = 0u; }
        int k = kb0 + o;
        int idx = r*160 + (swzb(k >> 3, r) << 3) + (k & 7);
        *(unsigned int*)(Ahi + idx) = hpack;
        *(unsigned int*)(Alo + idx) = lpack;
      }
    }
    __syncthreads();
    // ---- MFMA phase: 5 k-steps of 32 ----
    #pragma unroll
    for (int ksl = 0; ksl < 5; ksl++){
      const int ks = c*5 + ksl;
      short8 ah[2], al[2];
      #pragma unroll
      for (int mt = 0; mt < 2; mt++){
        int rr = wm*32 + mt*16 + l15;
        int kb = ksl*4 + q;
        int idx = rr*160 + (swzb(kb, rr) << 3);
        ah[mt] = *(const short8*)(Ahi + idx);
        al[mt] = *(const short8*)(Alo + idx);
      }
      #pragma unroll
      for (int nt = 0; nt < 4; nt++){
        int fo = (((wn*4 + nt)*50 + ks)*64 + lane) << 3;
        short8 bh = *(const short8*)(BH + fo);
        short8 bl = *(const short8*)(BL + fo);
        #pragma unroll
        for (int mt = 0; mt < 2; mt++){
          acc[mt][nt] = __builtin_amdgcn_mfma_f32_16x16x32_bf16(ah[mt], bh, acc[mt][nt], 0, 0, 0);
          acc[mt][nt] = __builtin_amdgcn_mfma_f32_16x16x32_bf16(al[mt], bh, acc[mt][nt], 0, 0, 0);
          acc[mt][nt] = __builtin_amdgcn_mfma_f32_16x16x32_bf16(ah[mt], bl, acc[mt][nt], 0, 0, 0);
        }
      }
    }
  }

  // ---- e1 = relu(acc + e1_b) -> LDS [64][132] f32 (16B-aligned rows) ----
  __syncthreads();
  float* e1buf = lds;
  #pragma unroll
  for (int mt = 0; mt < 2; mt++){
    #pragma unroll
    for (int nt = 0; nt < 4; nt++){
      int col = wn*64 + nt*16 + l15;
      float bias = ws[WS_E1B + col];
      #pragma unroll
      for (int r2 = 0; r2 < 4; r2++){
        int row = wm*32 + mt*16 + q*4 + r2;
        float v = acc[mt][nt][r2] + bias;
        e1buf[row*132 + col] = v > 0.0f ? v : 0.0f;
      }
    }
  }
  __syncthreads();

  // ---- folded enc2 via f16-split MFMA: zp = EPW . e1 + bias ----
  // wave gu handles batch rows gu*16..gu*16+15 (A: m=l15=batch, k over q*8+j)
  {
    half8 eh[4], el[4];
    const int myrow = gu*16 + l15;
    #pragma unroll
    for (int kc = 0; kc < 4; kc++){
      const float* ep = e1buf + myrow*132 + kc*32 + q*8;
      f32x4 va = *(const f32x4*)(ep);
      f32x4 vb = *(const f32x4*)(ep + 4);
      float v[8] = {va[0],va[1],va[2],va[3],vb[0],vb[1],vb[2],vb[3]};
      union { unsigned int u[4]; half8 h8; } H, L;
      #pragma unroll
      for (int p = 0; p < 4; p++){
        unsigned int h = pk_f16(v[2*p], v[2*p+1]);
        float r0 = v[2*p]   - f16lo(h);
        float r1 = v[2*p+1] - f16hi(h);
        H.u[p] = h;
        L.u[p] = pk_f16(r0, r1);
      }
      eh[kc] = H.h8; el[kc] = L.h8;
    }
    const unsigned short* EPH = (const unsigned short*)(ws + WS_EPWH);
    const unsigned short* EPL = (const unsigned short*)(ws + WS_EPWL);
    #pragma unroll 1
    for (int nt = 0; nt < 6; nt++){
      f32x4 c1 = (f32x4){0.f,0.f,0.f,0.f};
      f32x4 c2 = (f32x4){0.f,0.f,0.f,0.f};
      #pragma unroll
      for (int kc = 0; kc < 4; kc++){
        int fo = (((nt*4 + kc)*64 + lane)) << 3;
        half8 bh = *(const half8*)(EPH + fo);
        half8 bl = *(const half8*)(EPL + fo);
        c1 = __builtin_amdgcn_mfma_f32_16x16x32_f16(eh[kc], bh, c1, 0, 0, 0);
        c1 = __builtin_amdgcn_mfma_f32_16x16x32_f16(el[kc], bh, c1, 0, 0, 0);
        c2 = __builtin_amdgcn_mfma_f32_16x16x32_f16(eh[kc], bl, c2, 0, 0, 0);
      }
      float bias = (nt < 4) ? ws[WS_EBZ + nt*16 + l15] : ws[WS_PB + (nt-4)*16 + l15];
      #pragma unroll
      for (int rr = 0; rr < 4; rr++){
        zp0[(long)(rowbase + gu*16 + q*4 + rr)*96 + nt*16 + l15]
            = c1[rr] + c2[rr]*(1.0f/2048.0f) + bias;
      }
    }
  }
}

// ---------------- k2: 50 dopri5 steps (operand-swapped, barrier-free) -----
// 1 wave/block, 16 batch rows. D = Mz·u^T: A = Mz (static regs), B = u.
// State layout: batch = lane&15, hid dim = mt*16 + q*4 + r (in regs).
// Stage inputs are fused into the tanh argument (no yt array) to keep peak
// register demand < 256 (VGPR+AGPR unified budget at 2 waves/EU).
__launch_bounds__(64, 2)
__global__ void k2_ode(const float* __restrict__ ws,
                       const float* __restrict__ zp0,
                       float* __restrict__ out){
  __shared__ unsigned int scr[1152];        // Uh[576] + Ul[576] (16 x 36 u32 each)
  unsigned int* Uh = scr;
  unsigned int* Ul = scr + 576;
  const int tid = threadIdx.x;
  const int l15 = tid & 15, q = tid >> 4;
  const int hswz = (l15 & 1) << 4;          // bank swizzle: XOR slot bit4
  const int rowbase = blockIdx.x * 16;

  // Mz A-frags: value = Mz[mt*16+l15][kc*32+q*8+j]
  short8 Ah[4][2], Al[4][2];
  {
    const short8* pmh = (const short8*)(ws + WS_MZH);
    const short8* pml = (const short8*)(ws + WS_MZL);
    #pragma unroll
    for (int mt = 0; mt < 4; mt++)
      #pragma unroll
      for (int kc = 0; kc < 2; kc++){
        int idx = (mt*16 + l15)*8 + kc*4 + q;
        Ah[mt][kc] = pmh[idx];
        Al[mt][kc] = pml[idx];
      }
  }
  float b1a[16], cza[16];
  #pragma unroll
  for (int mt = 0; mt < 4; mt++){
    f32x4 b  = *(const f32x4*)(ws + WS_B1 + mt*16 + q*4);
    f32x4 cz = *(const f32x4*)(ws + WS_CZ + mt*16 + q*4);
    #pragma unroll
    for (int rr = 0; rr < 4; rr++){ b1a[mt*4+rr] = b[rr]; cza[mt*4+rr] = cz[rr]; }
  }
  const float dt = ws[WS_DT];

  float z[16], s[16];
  #pragma unroll
  for (int mt = 0; mt < 4; mt++){
    f32x4 v = *(const f32x4*)(zp0 + (long)(rowbase + l15)*96 + mt*16 + q*4);
    #pragma unroll
    for (int rr = 0; rr < 4; rr++){ z[mt*4+rr] = v[rr]; s[mt*4+rr] = 0.0f; }
  }

  const int wbase = l15*36;

  // feval: stage input supplied per-element by `sin(i)` (fused, no yt array)
  auto feval = [&](auto sin, float* g, float w){
    #pragma unroll
    for (int mt = 0; mt < 4; mt++){
      float u0 = tanh5(sin(mt*4+0) + b1a[mt*4+0]);
      float u1 = tanh5(sin(mt*4+1) + b1a[mt*4+1]);
      float u2 = tanh5(sin(mt*4+2) + b1a[mt*4+2]);
      float u3 = tanh5(sin(mt*4+3) + b1a[mt*4+3]);
      if (w != 0.0f){
        s[mt*4+0] += w*u0; s[mt*4+1] += w*u1;
        s[mt*4+2] += w*u2; s[mt*4+3] += w*u3;
      }
      unsigned int h01, lo01, h23, lo23;
      split_pair(u0, u1, h01, lo01);
      split_pair(u2, u3, h23, lo23);
      int slot = wbase + ((8*mt + 2*q) ^ hswz);
      *(uint2*)(Uh + slot) = make_uint2(h01, h23);
      *(uint2*)(Ul + slot) = make_uint2(lo01, lo23);
    }
    f32x4 c[4];
    #pragma unroll
    for (int mt = 0; mt < 4; mt++) c[mt] = (f32x4){0.f,0.f,0.f,0.f};
    #pragma unroll
    for (int kc = 0; kc < 2; kc++){
      int rb = wbase + ((16*kc + 4*q) ^ hswz);
      short8 bh = *(const short8*)(Uh + rb);
      short8 bl = *(const short8*)(Ul + rb);
      #pragma unroll
      for (int mt = 0; mt < 4; mt++){
        c[mt] = __builtin_amdgcn_mfma_f32_16x16x32_bf16(Ah[mt][kc], bh, c[mt], 0, 0, 0);
        c[mt] = __builtin_amdgcn_mfma_f32_16x16x32_bf16(Al[mt][kc], bh, c[mt], 0, 0, 0);
        c[mt] = __builtin_amdgcn_mfma_f32_16x16x32_bf16(Ah[mt][kc], bl, c[mt], 0, 0, 0);
      }
    }
    #pragma unroll
    for (int i = 0; i < 16; i++) g[i] = c[i>>2][i&3] + cza[i];
  };

  // tableau (g2 folded into A = c31*g1 + c32*g2; g6 reuses A)
  const float c21 = dt * 0.2f;
  const float c31 = dt * (3.0f/40.0f),  c32 = dt * (9.0f/40.0f);
  const float c43 = dt * (32.0f/9.0f);
  const float c53 = dt * (64448.0f/6561.0f), c54 = dt * (-212.0f/729.0f);
  const float c63 = dt * (46732.0f/5247.0f), c64 = dt * (49.0f/176.0f),
              c65 = dt * (-5103.0f/18656.0f);
  const float r42 = -448.0f/27.0f,          c41p = dt * (20.0f/9.0f);
  const float r52 = -1014400.0f/19683.0f,   c51p = dt * (134196.0f/19683.0f);
  const float r62 = -14200.0f/297.0f,       c61p = dt * (9017.0f/3168.0f + 42600.0f/11880.0f);
  const float d1 = dt * (35.0f/384.0f), d3 = dt * (500.0f/1113.0f), d4 = dt * (125.0f/192.0f),
              d5 = dt * (-2187.0f/6784.0f), d6 = dt * (11.0f/84.0f);

  float g1[16], A[16], g3[16], g4[16], g5[16];

  #pragma unroll 1
  for (int st = 0; st < NSTEPS; st++){
    feval([&](int i){ return z[i]; }, g1, d1);
    feval([&](int i){ return z[i] + c21*g1[i]; }, A, 0.0f);
    #pragma unroll
    for (int i = 0; i < 16; i++) A[i] = c31*g1[i] + c32*A[i];
    feval([&](int i){ return z[i] + A[i]; }, g3, d3);
    feval([&](int i){ return z[i] + r42*A[i] + c41p*g1[i] + c43*g3[i]; }, g4, d4);
    feval([&](int i){ return z[i] + r52*A[i] + c51p*g1[i] + c53*g3[i] + c54*g4[i]; }, g5, d5);
    feval([&](int i){ return z[i] + r62*A[i] + c61p*g1[i] + c63*g3[i] + c64*g4[i] + c65*g5[i]; },
          A, d6);   // A := g6 (stage input reads A before g write — safe)
    #pragma unroll
    for (int i = 0; i < 16; i++) z[i] += d1*g1[i] + d3*g3[i] + d4*g4[i] + d5*g5[i] + d6*A[i];
  }

  // ---- regressor: r = relu(p0 + Q*s + cb); out = reg2.r + r2b ----
  {
    #pragma unroll
    for (int mt = 0; mt < 4; mt++){
      unsigned int h01, lo01, h23, lo23;
      split_pair(s[mt*4+0], s[mt*4+1], h01, lo01);
      split_pair(s[mt*4+2], s[mt*4+3], h23, lo23);
      int slot = wbase + ((8*mt + 2*q) ^ hswz);
      *(uint2*)(Uh + slot) = make_uint2(h01, h23);
      *(uint2*)(Ul + slot) = make_uint2(lo01, lo23);
    }
    const short8* pqh = (const short8*)(ws + WS_QH);
    const short8* pql = (const short8*)(ws + WS_QL);
    f32x4 cv[2];
    cv[0] = (f32x4){0.f,0.f,0.f,0.f};
    cv[1] = (f32x4){0.f,0.f,0.f,0.f};
    #pragma unroll
    for (int kc = 0; kc < 2; kc++){
      int rb = wbase + ((16*kc + 4*q) ^ hswz);
      short8 bh = *(const short8*)(Uh + rb);
      short8 bl = *(const short8*)(Ul + rb);
      #pragma unroll
      for (int mt2 = 0; mt2 < 2; mt2++){
        int idx = (mt2*16 + l15)*8 + kc*4 + q;
        short8 qh = pqh[idx];
        short8 qlf = pql[idx];
        cv[mt2] = __builtin_amdgcn_mfma_f32_16x16x32_bf16(qh,  bh, cv[mt2], 0, 0, 0);
        cv[mt2] = __builtin_amdgcn_mfma_f32_16x16x32_bf16(qlf, bh, cv[mt2], 0, 0, 0);
        cv[mt2] = __builtin_amdgcn_mfma_f32_16x16x32_bf16(qh,  bl, cv[mt2], 0, 0, 0);
      }
    }
    float part = 0.f;
    #pragma unroll
    for (int mt2 = 0; mt2 < 2; mt2++){
      f32x4 cb = *(const f32x4*)(ws + WS_CB2 + mt2*16 + q*4);
      f32x4 p0 = *(const f32x4*)(zp0 + (long)(rowbase + l15)*96 + 64 + mt2*16 + q*4);
      f32x4 w2 = *(const f32x4*)(ws + WS_R2W + mt2*16 + q*4);
      #pragma unroll
      for (int rr = 0; rr < 4; rr++){
        float v = cv[mt2][rr] + cb[rr] + p0[rr];
        v = v > 0.0f ? v : 0.0f;
        part += w2[rr] * v;
      }
    }
    part += __shfl_xor(part, 16);
    part += __shfl_xor(part, 32);
    if (q == 0) out[rowbase + l15] = part + ws[WS_R2B];
  }
}

// ---------------------------------------------------------------------------
extern "C" void kernel_launch(void* const* d_in, const int* in_sizes, int n_in,
                              void* d_out, int out_size, void* d_ws, size_t ws_size,
                              hipStream_t stream){
  (void)in_sizes; (void)n_in; (void)out_size; (void)ws_size;
  float* ws = (float*)d_ws;

  k_detect<<<dim3(1), dim3(64), 0, stream>>>(d_in[0], d_in[1], ws);
  k0_convert<<<dim3(64), dim3(256), 0, stream>>>(
      d_in[2], d_in[3], d_in[4], d_in[5], d_in[6], d_in[7],
      d_in[8], d_in[9], d_in[10], d_in[11], d_in[12], d_in[13],
      d_in[14], d_in[15], ws);
  k1_encoder<<<dim3(BTOT/64), dim3(256), 0, stream>>>(d_in[0], ws, ws + WS_ZP0);
  k2_ode<<<dim3(BTOT/16), dim3(64), 0, stream>>>(ws, ws + WS_ZP0, (float*)d_out);
}

// Round 5
// 1915.611 us; speedup vs baseline: 1.2996x; 1.2149x over previous
//
#include <hip/hip_runtime.h>
#include <hip/hip_bf16.h>

typedef __attribute__((ext_vector_type(8))) short short8;
typedef __attribute__((ext_vector_type(4))) float f32x4;
typedef __attribute__((ext_vector_type(2))) __fp16 fp16x2;
typedef __attribute__((ext_vector_type(8))) _Float16 half8;

#define SEQ 40
#define IN_DIM 24
#define NKER 36
#define ENC 128
#define HID 64
#define NSTEPS 50
#define BTOT 65536

// ---- ws float-element offsets ----
#define WS_FLAG 0
#define WS_DT   1
#define WS_CW   16        // [36][3][24] f32
#define WS_CB   2608      // [36]
#define WS_E1B  2644      // [128]
#define WS_B1   2772      // [64]  ode1_b
#define WS_CZ   2836      // [64]  W1*b2
#define WS_CB2  2900      // [32]  T*reg1*b2 + reg1_b
#define WS_R2W  2932      // [32]
#define WS_R2B  2964      // [1]
#define WS_EBZ  2976      // [64]  W1*enc2_b
#define WS_PB   3040      // [32]  reg1*enc2_b
// enc1 weights in MFMA B-fragment order, k' = s*40 + o (o padded to 40), K=1600
#define WS_BH   4096      // 204800 ushorts (hi)
#define WS_BL   106496    // 204800 ushorts (lo)
#define WS_MZH  221184    // [64][64] bf16 hi (2048 f) frag-order n*8+kc*4+q
#define WS_MZL  223232    // [64][64] bf16 lo
#define WS_QH   225280    // [32][64] bf16 hi (1024 f)
#define WS_QL   226304    // [32][64] bf16 lo
// folded enc2 weights [96][128] as f16 MFMA B-frags: [nt:6][kc:4][lane:64][j:8]
#define WS_EPWH 227328    // 12288 ushorts = 6144 f (f16 hi)
#define WS_EPWL 233472    // 12288 ushorts = 6144 f (f16 lo * 2048)
#define WS_ZP0  262144    // [B][96] f32: z0[64] + p0[32] per row

__device__ __forceinline__ unsigned short f2bf(float f){   // RNE
  union { float f; unsigned int u; } v; v.f = f;
  unsigned int r = (v.u + 0x7FFFu + ((v.u >> 16) & 1u)) >> 16;
  return (unsigned short)r;
}
__device__ __forceinline__ float bf2f(unsigned short s){
  union { unsigned int u; float f; } v; v.u = ((unsigned int)s) << 16; return v.f;
}
// packed bf16 pair (RNE) via hardware cvt
__device__ __forceinline__ unsigned int pk_bf16(float a, float b){
  unsigned int r;
  asm("v_cvt_pk_bf16_f32 %0, %1, %2" : "=v"(r) : "v"(a), "v"(b));
  return r;
}
// split pair into hi-pack + lo-pack (hi RNE, lo RNE) — 6 VALU ops
__device__ __forceinline__ void split_pair(float v0, float v1,
                                           unsigned int& h, unsigned int& lo){
  h = pk_bf16(v0, v1);
  union { unsigned int u; float f; } a, b;
  a.u = h << 16; b.u = h & 0xffff0000u;
  lo = pk_bf16(v0 - a.f, v1 - b.f);
}
// f16 helpers
__device__ __forceinline__ unsigned int pk_f16(float a, float b){
  fp16x2 h = __builtin_amdgcn_cvt_pkrtz(a, b);
  union { fp16x2 h; unsigned int u; } cv; cv.h = h; return cv.u;
}
__device__ __forceinline__ float f16lo(unsigned int u){
  union { unsigned short s; __fp16 h; } c; c.s = (unsigned short)(u & 0xffffu);
  return (float)c.h;
}
__device__ __forceinline__ float f16hi(unsigned int u){
  union { unsigned short s; __fp16 h; } c; c.s = (unsigned short)(u >> 16);
  return (float)c.h;
}
// tanh(x) = 1 - 2/(e^{2x}+1): 5 VALU ops
__device__ __forceinline__ float tanh5(float x){
  float e = __builtin_exp2f(x * 2.885390081777927f);   // e^{2x}
  float r = __builtin_amdgcn_rcpf(1.0f + e);
  return __builtin_fmaf(-2.0f, r, 1.0f);
}

// ---------------- detector ----------------
__global__ void k_detect(const void* __restrict__ x, const void* __restrict__ t_span,
                         float* __restrict__ ws){
  const unsigned int* xw = (const unsigned int*)x;
  int lane = threadIdx.x;
  int cnt = 0;
  #pragma unroll
  for (int i = 0; i < 16; i++){
    unsigned int w = xw[lane * 16 + i];
    unsigned int e = (w >> 7) & 0xFFu;
    cnt += (e >= 100u && e <= 140u) ? 1 : 0;
  }
  #pragma unroll
  for (int off = 32; off; off >>= 1) cnt += __shfl_down(cnt, off);
  if (lane == 0){
    int flag = (cnt >= 700) ? 1 : 0;
    float t0, t1;
    if (flag){
      t0 = __bfloat162float(((const __hip_bfloat16*)t_span)[0]);
      t1 = __bfloat162float(((const __hip_bfloat16*)t_span)[1]);
    } else {
      t0 = ((const float*)t_span)[0];
      t1 = ((const float*)t_span)[1];
    }
    ws[WS_FLAG] = (float)flag;
    ws[WS_DT] = (t1 - t0) / (float)NSTEPS;
  }
}

// ---------------- k0: weight convert + algebraic folds + frag packs ------
__global__ void k0_convert(const void* __restrict__ conv_w, const void* __restrict__ conv_b,
                           const void* __restrict__ enc1_w, const void* __restrict__ enc1_b,
                           const void* __restrict__ enc2_w, const void* __restrict__ enc2_b,
                           const void* __restrict__ ode1_w, const void* __restrict__ ode1_b,
                           const void* __restrict__ ode2_w, const void* __restrict__ ode2_b,
                           const void* __restrict__ reg1_w, const void* __restrict__ reg1_b,
                           const void* __restrict__ reg2_w, const void* __restrict__ reg2_b,
                           float* __restrict__ ws){
  const int flag = (int)ws[WS_FLAG];
  const float T = ws[WS_DT] * (float)NSTEPS;
  int t = blockIdx.x * 256 + threadIdx.x;
  int stride = gridDim.x * 256;

  #define RD(src, i) (flag ? __bfloat162float(((const __hip_bfloat16*)(src))[i]) \
                           : ((const float*)(src))[i])

  for (int i = t; i < NKER*72; i += stride){
    int o = i / 72, r = i % 72, dk = r / 24, c = r % 24;
    ws[WS_CW + i] = RD(conv_w, o*72 + c*3 + dk);
  }
  for (int i = t; i < NKER; i += stride) ws[WS_CB + i] = RD(conv_b, i);
  for (int i = t; i < ENC; i += stride) ws[WS_E1B + i] = RD(enc1_b, i);

  // enc1 B-fragments (split hi/lo bf16), k' = s*40 + o  (o in [36,40) -> 0)
  {
    unsigned short* bh = (unsigned short*)(ws + WS_BH);
    unsigned short* bl = (unsigned short*)(ws + WS_BL);
    for (int i = t; i < 8*50*64*8; i += stride){
      int j = i & 7, l = (i >> 3) & 63;
      int rem = i >> 9, ks = rem % 50, nt = rem / 50;
      int n = nt*16 + (l & 15);
      int kk = ks*32 + (l >> 4)*8 + j;
      int s = kk / 40, o = kk % 40;
      float v = (o < 36) ? RD(enc1_w, n*1440 + o*40 + s) : 0.0f;
      unsigned short h = f2bf(v);
      bh[i] = h; bl[i] = f2bf(v - bf2f(h));
    }
  }

  // folded enc2 [96][128] = [W1;reg1]*enc2_w, f16 B-frags, lo scaled x2048
  {
    unsigned short* eph = (unsigned short*)(ws + WS_EPWH);
    unsigned short* epl = (unsigned short*)(ws + WS_EPWL);
    for (int i = t; i < 6*4*64*8; i += stride){
      int j = i & 7, l = (i >> 3) & 63, kc = (i >> 9) & 3, nt = i >> 11;
      int n = nt*16 + (l & 15);
      int k = kc*32 + (l >> 4)*8 + j;
      float acc = 0.f;
      if (n < 64){
        for (int h = 0; h < 64; h++) acc += RD(ode1_w, n*64+h) * RD(enc2_w, h*128+k);
      } else {
        int p = n - 64;
        for (int h = 0; h < 64; h++) acc += RD(reg1_w, p*64+h) * RD(enc2_w, h*128+k);
      }
      unsigned int hp = pk_f16(acc, 0.f);
      float hf = f16lo(hp);
      unsigned int lp = pk_f16((acc - hf) * 2048.0f, 0.f);
      eph[i] = (unsigned short)(hp & 0xffffu);
      epl[i] = (unsigned short)(lp & 0xffffu);
    }
  }

  for (int i = t; i < 64; i += stride){
    float acc = 0.f;
    for (int h = 0; h < 64; h++) acc += RD(ode1_w, i*64+h) * RD(enc2_b, h);
    ws[WS_EBZ + i] = acc;
    float acc2 = 0.f;
    for (int h = 0; h < 64; h++) acc2 += RD(ode1_w, i*64+h) * RD(ode2_b, h);
    ws[WS_CZ + i] = acc2;
    ws[WS_B1 + i] = RD(ode1_b, i);
  }
  for (int i = t; i < 32; i += stride){
    float acc = 0.f;
    for (int h = 0; h < 64; h++) acc += RD(reg1_w, i*64+h) * RD(enc2_b, h);
    ws[WS_PB + i] = acc;
    float acc2 = 0.f;
    for (int h = 0; h < 64; h++) acc2 += RD(reg1_w, i*64+h) * RD(ode2_b, h);
    ws[WS_CB2 + i] = T * acc2 + RD(reg1_b, i);
    ws[WS_R2W + i] = RD(reg2_w, i);
  }
  if (t == 0) ws[WS_R2B] = RD(reg2_b, 0);

  // Mz = W1*W2 [64][64], split hi/lo bf16 (frag order: unit = n*8 + kc*4 + q)
  unsigned short* mzh = (unsigned short*)(ws + WS_MZH);
  unsigned short* mzl = (unsigned short*)(ws + WS_MZL);
  for (int i = t; i < 64*64; i += stride){
    int a = i >> 6, b = i & 63;
    float acc = 0.f;
    for (int h = 0; h < 64; h++) acc += RD(ode1_w, a*64+h) * RD(ode2_w, h*64+b);
    unsigned short hi = f2bf(acc);
    mzh[i] = hi; mzl[i] = f2bf(acc - bf2f(hi));
  }
  // Q = reg1*W2 [32][64], split hi/lo bf16
  unsigned short* qh = (unsigned short*)(ws + WS_QH);
  unsigned short* ql = (unsigned short*)(ws + WS_QL);
  for (int i = t; i < 32*64; i += stride){
    int p = i >> 6, b = i & 63;
    float acc = 0.f;
    for (int h = 0; h < 64; h++) acc += RD(reg1_w, p*64+h) * RD(ode2_w, h*64+b);
    unsigned short hi = f2bf(acc);
    qh[i] = hi; ql[i] = f2bf(acc - bf2f(hi));
  }
  #undef RD
}

// ---------------- k1: conv+silu -> MFMA enc1 -> MFMA folded enc2 ----------
// 1024 blocks x 256 thr (4 waves), 64 rows/block.
__launch_bounds__(256, 4)
__global__ void k1_encoder(const void* __restrict__ x,
                           const float* __restrict__ ws,
                           float* __restrict__ zp0){
  __shared__ float lds[10240];                       // 40 KB: Ahi/Alo, later e1[64][132]
  unsigned short* Ahi = (unsigned short*)lds;        // [64][160] ushort
  unsigned short* Alo = Ahi + 64*160;
  const int flag = (int)ws[WS_FLAG];
  const int t = threadIdx.x;
  const int lane = t & 63;
  const int gu = __builtin_amdgcn_readfirstlane(t >> 6);   // wave id, SGPR
  const int wm = gu >> 1, wn = gu & 1;
  const int l15 = lane & 15, q = lane >> 4;
  const int r = lane;                                // conv row 0..63
  const long rowbase = (long)blockIdx.x * 64;

  f32x4 acc[2][4];
  #pragma unroll
  for (int mt = 0; mt < 2; mt++)
    #pragma unroll
    for (int nt = 0; nt < 4; nt++)
      acc[mt][nt] = (f32x4){0.f, 0.f, 0.f, 0.f};

  const unsigned short* BH = (const unsigned short*)(ws + WS_BH);
  const unsigned short* BL = (const unsigned short*)(ws + WS_BL);
  const float* CW = ws + WS_CW;
  const float* CB = ws + WS_CB;

  float xc[24];
  auto loadcol = [&](int col){
    if (col >= 0 && col < SEQ){
      if (flag){
        const __hip_bfloat16* xp = (const __hip_bfloat16*)x + (rowbase + r)*(SEQ*IN_DIM) + col*IN_DIM;
        const uint4* px = (const uint4*)xp;
        #pragma unroll
        for (int w8 = 0; w8 < 3; w8++){
          uint4 u = px[w8];
          unsigned int uu[4] = {u.x, u.y, u.z, u.w};
          #pragma unroll
          for (int e = 0; e < 4; e++){
            union { unsigned int i; float f; } lo, hi;
            lo.i = uu[e] << 16; hi.i = uu[e] & 0xffff0000u;
            xc[w8*8 + 2*e] = lo.f; xc[w8*8 + 2*e + 1] = hi.f;
          }
        }
      } else {
        const float* xp = (const float*)x + (rowbase + r)*(SEQ*IN_DIM) + col*IN_DIM;
        #pragma unroll
        for (int w4 = 0; w4 < 6; w4++){
          float4 v = ((const float4*)xp)[w4];
          xc[4*w4] = v.x; xc[4*w4+1] = v.y; xc[4*w4+2] = v.z; xc[4*w4+3] = v.w;
        }
      }
    } else {
      #pragma unroll
      for (int cc = 0; cc < 24; cc++) xc[cc] = 0.f;
    }
  };

  auto swzb = [](int blk, int rw){ return blk ^ ((blk < 16) ? (rw & 7) : (rw & 3)); };

  #pragma unroll 1
  for (int c = 0; c < 10; c++){
    __syncthreads();   // prev chunk's MFMA reads done (cross-wave)
    // ---- conv phase: row r, s-column = c*4 + gu ----
    {
      const int s = c*4 + gu;
      float accv[36];
      #pragma unroll
      for (int o = 0; o < 36; o++) accv[o] = CB[o];
      #pragma unroll 1
      for (int dk = 0; dk < 3; dk++){
        loadcol(s - 1 + dk);
        const float* wdk = CW + dk*24;
        #pragma unroll
        for (int o = 0; o < 36; o++){
          const float* wo = wdk + o*72;
          float a = accv[o];
          #pragma unroll
          for (int ci = 0; ci < 24; ci++) a += wo[ci] * xc[ci];
          accv[o] = a;
        }
      }
      const int kb0 = gu * 40;
      #pragma unroll
      for (int o = 0; o < 40; o += 2){
        unsigned int hpack, lpack;
        if (o < 36){
          float v0 = accv[o];     v0 = v0 * __builtin_amdgcn_rcpf(1.0f + __expf(-v0));
          float v1 = accv[o + 1]; v1 = v1 * __builtin_amdgcn_rcpf(1.0f + __expf(-v1));
          split_pair(v0, v1, hpack, lpack);
        } else { hpack = 0u; lpack = 0u; }
        int k = kb0 + o;
        int idx = r*160 + (swzb(k >> 3, r) << 3) + (k & 7);
        *(unsigned int*)(Ahi + idx) = hpack;
        *(unsigned int*)(Alo + idx) = lpack;
      }
    }
    __syncthreads();
    // ---- MFMA phase: 5 k-steps of 32 ----
    #pragma unroll
    for (int ksl = 0; ksl < 5; ksl++){
      const int ks = c*5 + ksl;
      short8 ah[2], al[2];
      #pragma unroll
      for (int mt = 0; mt < 2; mt++){
        int rr = wm*32 + mt*16 + l15;
        int kb = ksl*4 + q;
        int idx = rr*160 + (swzb(kb, rr) << 3);
        ah[mt] = *(const short8*)(Ahi + idx);
        al[mt] = *(const short8*)(Alo + idx);
      }
      #pragma unroll
      for (int nt = 0; nt < 4; nt++){
        int fo = (((wn*4 + nt)*50 + ks)*64 + lane) << 3;
        short8 bh = *(const short8*)(BH + fo);
        short8 bl = *(const short8*)(BL + fo);
        #pragma unroll
        for (int mt = 0; mt < 2; mt++){
          acc[mt][nt] = __builtin_amdgcn_mfma_f32_16x16x32_bf16(ah[mt], bh, acc[mt][nt], 0, 0, 0);
          acc[mt][nt] = __builtin_amdgcn_mfma_f32_16x16x32_bf16(al[mt], bh, acc[mt][nt], 0, 0, 0);
          acc[mt][nt] = __builtin_amdgcn_mfma_f32_16x16x32_bf16(ah[mt], bl, acc[mt][nt], 0, 0, 0);
        }
      }
    }
  }

  // ---- e1 = relu(acc + e1_b) -> LDS [64][132] f32 (16B-aligned rows) ----
  __syncthreads();
  float* e1buf = lds;
  #pragma unroll
  for (int mt = 0; mt < 2; mt++){
    #pragma unroll
    for (int nt = 0; nt < 4; nt++){
      int col = wn*64 + nt*16 + l15;
      float bias = ws[WS_E1B + col];
      #pragma unroll
      for (int r2 = 0; r2 < 4; r2++){
        int row = wm*32 + mt*16 + q*4 + r2;
        float v = acc[mt][nt][r2] + bias;
        e1buf[row*132 + col] = v > 0.0f ? v : 0.0f;
      }
    }
  }
  __syncthreads();

  // ---- folded enc2 via f16-split MFMA: zp = EPW . e1 + bias ----
  // wave gu handles batch rows gu*16..gu*16+15 (A: m=l15=batch, k over q*8+j)
  {
    half8 eh[4], el[4];
    const int myrow = gu*16 + l15;
    #pragma unroll
    for (int kc = 0; kc < 4; kc++){
      const float* ep = e1buf + myrow*132 + kc*32 + q*8;
      f32x4 va = *(const f32x4*)(ep);
      f32x4 vb = *(const f32x4*)(ep + 4);
      float v[8] = {va[0],va[1],va[2],va[3],vb[0],vb[1],vb[2],vb[3]};
      union { unsigned int u[4]; half8 h8; } H, L;
      #pragma unroll
      for (int p = 0; p < 4; p++){
        unsigned int h = pk_f16(v[2*p], v[2*p+1]);
        float r0 = v[2*p]   - f16lo(h);
        float r1 = v[2*p+1] - f16hi(h);
        H.u[p] = h;
        L.u[p] = pk_f16(r0, r1);
      }
      eh[kc] = H.h8; el[kc] = L.h8;
    }
    const unsigned short* EPH = (const unsigned short*)(ws + WS_EPWH);
    const unsigned short* EPL = (const unsigned short*)(ws + WS_EPWL);
    #pragma unroll 1
    for (int nt = 0; nt < 6; nt++){
      f32x4 c1 = (f32x4){0.f,0.f,0.f,0.f};
      f32x4 c2 = (f32x4){0.f,0.f,0.f,0.f};
      #pragma unroll
      for (int kc = 0; kc < 4; kc++){
        int fo = (((nt*4 + kc)*64 + lane)) << 3;
        half8 bh = *(const half8*)(EPH + fo);
        half8 bl = *(const half8*)(EPL + fo);
        c1 = __builtin_amdgcn_mfma_f32_16x16x32_f16(eh[kc], bh, c1, 0, 0, 0);
        c1 = __builtin_amdgcn_mfma_f32_16x16x32_f16(el[kc], bh, c1, 0, 0, 0);
        c2 = __builtin_amdgcn_mfma_f32_16x16x32_f16(eh[kc], bl, c2, 0, 0, 0);
      }
      float bias = (nt < 4) ? ws[WS_EBZ + nt*16 + l15] : ws[WS_PB + (nt-4)*16 + l15];
      #pragma unroll
      for (int rr = 0; rr < 4; rr++){
        zp0[(long)(rowbase + gu*16 + q*4 + rr)*96 + nt*16 + l15]
            = c1[rr] + c2[rr]*(1.0f/2048.0f) + bias;
      }
    }
  }
}

// ---------------- k2: 50 dopri5 steps (operand-swapped, barrier-free) -----
// 1 wave/block, 16 batch rows. D = Mz·u^T: A = Mz (LDS-staged), B = u.
// State layout: batch = lane&15, hid dim = mt*16 + q*4 + r (in regs).
// Mz frags live in LDS (block-invariant, 16 KB, chunk-major => stride-1
// conflict-free b128 on both stage and read) to keep register demand < 256.
__launch_bounds__(64, 2)
__global__ void k2_ode(const float* __restrict__ ws,
                       const float* __restrict__ zp0,
                       float* __restrict__ out){
  __shared__ unsigned int lds_all[1152 + 4096]; // scr[1152] + MzH/MzL 16KB
  unsigned int* Uh = lds_all;
  unsigned int* Ul = lds_all + 576;
  const short8* MzHl = (const short8*)(lds_all + 1152);   // 512 units
  const short8* MzLl = MzHl + 512;
  const int tid = threadIdx.x;
  const int l15 = tid & 15, q = tid >> 4;
  const int hswz = (l15 & 1) << 4;          // bank swizzle: XOR slot bit4
  const int rowbase = blockIdx.x * 16;

  // stage Mz frags: global unit = row*8 + cc  ->  LDS unit = cc*64 + row
  {
    const uint4* gh = (const uint4*)(ws + WS_MZH);
    const uint4* gl = (const uint4*)(ws + WS_MZL);
    uint4* dh = (uint4*)(lds_all + 1152);
    uint4* dl = dh + 512;
    #pragma unroll
    for (int cc = 0; cc < 8; cc++){
      dh[cc*64 + tid] = gh[tid*8 + cc];
      dl[cc*64 + tid] = gl[tid*8 + cc];
    }
  }

  float b1a[16], cza[16];
  #pragma unroll
  for (int mt = 0; mt < 4; mt++){
    f32x4 b  = *(const f32x4*)(ws + WS_B1 + mt*16 + q*4);
    f32x4 cz = *(const f32x4*)(ws + WS_CZ + mt*16 + q*4);
    #pragma unroll
    for (int rr = 0; rr < 4; rr++){ b1a[mt*4+rr] = b[rr]; cza[mt*4+rr] = cz[rr]; }
  }
  const float dt = ws[WS_DT];

  float z[16], s[16];
  #pragma unroll
  for (int mt = 0; mt < 4; mt++){
    f32x4 v = *(const f32x4*)(zp0 + (long)(rowbase + l15)*96 + mt*16 + q*4);
    #pragma unroll
    for (int rr = 0; rr < 4; rr++){ z[mt*4+rr] = v[rr]; s[mt*4+rr] = 0.0f; }
  }

  const int wbase = l15*36;
  const int mzbase = q*64 + l15;            // + kc*256 + mt*16

  // feval: stage input supplied per-element by `sin(i)` (fused, no yt array)
  auto feval = [&](auto sin, float* g, float w){
    #pragma unroll
    for (int mt = 0; mt < 4; mt++){
      float u0 = tanh5(sin(mt*4+0) + b1a[mt*4+0]);
      float u1 = tanh5(sin(mt*4+1) + b1a[mt*4+1]);
      float u2 = tanh5(sin(mt*4+2) + b1a[mt*4+2]);
      float u3 = tanh5(sin(mt*4+3) + b1a[mt*4+3]);
      if (w != 0.0f){
        s[mt*4+0] += w*u0; s[mt*4+1] += w*u1;
        s[mt*4+2] += w*u2; s[mt*4+3] += w*u3;
      }
      unsigned int h01, lo01, h23, lo23;
      split_pair(u0, u1, h01, lo01);
      split_pair(u2, u3, h23, lo23);
      int slot = wbase + ((8*mt + 2*q) ^ hswz);
      *(uint2*)(Uh + slot) = make_uint2(h01, h23);
      *(uint2*)(Ul + slot) = make_uint2(lo01, lo23);
    }
    f32x4 c[4];
    #pragma unroll
    for (int mt = 0; mt < 4; mt++) c[mt] = (f32x4){0.f,0.f,0.f,0.f};
    #pragma unroll
    for (int kc = 0; kc < 2; kc++){
      int rb = wbase + ((16*kc + 4*q) ^ hswz);
      short8 bh = *(const short8*)(Uh + rb);
      short8 bl = *(const short8*)(Ul + rb);
      #pragma unroll
      for (int mt = 0; mt < 4; mt++){
        short8 ah = MzHl[mzbase + kc*256 + mt*16];
        short8 al = MzLl[mzbase + kc*256 + mt*16];
        c[mt] = __builtin_amdgcn_mfma_f32_16x16x32_bf16(ah, bh, c[mt], 0, 0, 0);
        c[mt] = __builtin_amdgcn_mfma_f32_16x16x32_bf16(al, bh, c[mt], 0, 0, 0);
        c[mt] = __builtin_amdgcn_mfma_f32_16x16x32_bf16(ah, bl, c[mt], 0, 0, 0);
      }
    }
    #pragma unroll
    for (int i = 0; i < 16; i++) g[i] = c[i>>2][i&3] + cza[i];
  };

  // tableau (g2 folded into A = c31*g1 + c32*g2; g6 reuses A)
  const float c21 = dt * 0.2f;
  const float c31 = dt * (3.0f/40.0f),  c32 = dt * (9.0f/40.0f);
  const float c43 = dt * (32.0f/9.0f);
  const float c53 = dt * (64448.0f/6561.0f), c54 = dt * (-212.0f/729.0f);
  const float c63 = dt * (46732.0f/5247.0f), c64 = dt * (49.0f/176.0f),
              c65 = dt * (-5103.0f/18656.0f);
  const float r42 = -448.0f/27.0f,          c41p = dt * (20.0f/9.0f);
  const float r52 = -1014400.0f/19683.0f,   c51p = dt * (134196.0f/19683.0f);
  const float r62 = -14200.0f/297.0f,       c61p = dt * (9017.0f/3168.0f + 42600.0f/11880.0f);
  const float d1 = dt * (35.0f/384.0f), d3 = dt * (500.0f/1113.0f), d4 = dt * (125.0f/192.0f),
              d5 = dt * (-2187.0f/6784.0f), d6 = dt * (11.0f/84.0f);

  float g1[16], A[16], g3[16], g4[16], g5[16];

  #pragma unroll 1
  for (int st = 0; st < NSTEPS; st++){
    feval([&](int i){ return z[i]; }, g1, d1);
    feval([&](int i){ return z[i] + c21*g1[i]; }, A, 0.0f);
    #pragma unroll
    for (int i = 0; i < 16; i++) A[i] = c31*g1[i] + c32*A[i];
    feval([&](int i){ return z[i] + A[i]; }, g3, d3);
    feval([&](int i){ return z[i] + r42*A[i] + c41p*g1[i] + c43*g3[i]; }, g4, d4);
    feval([&](int i){ return z[i] + r52*A[i] + c51p*g1[i] + c53*g3[i] + c54*g4[i]; }, g5, d5);
    feval([&](int i){ return z[i] + r62*A[i] + c61p*g1[i] + c63*g3[i] + c64*g4[i] + c65*g5[i]; },
          A, d6);   // A := g6 (stage input reads A before g write — safe)
    #pragma unroll
    for (int i = 0; i < 16; i++) z[i] += d1*g1[i] + d3*g3[i] + d4*g4[i] + d5*g5[i] + d6*A[i];
  }

  // ---- regressor: r = relu(p0 + Q*s + cb); out = reg2.r + r2b ----
  {
    #pragma unroll
    for (int mt = 0; mt < 4; mt++){
      unsigned int h01, lo01, h23, lo23;
      split_pair(s[mt*4+0], s[mt*4+1], h01, lo01);
      split_pair(s[mt*4+2], s[mt*4+3], h23, lo23);
      int slot = wbase + ((8*mt + 2*q) ^ hswz);
      *(uint2*)(Uh + slot) = make_uint2(h01, h23);
      *(uint2*)(Ul + slot) = make_uint2(lo01, lo23);
    }
    const short8* pqh = (const short8*)(ws + WS_QH);
    const short8* pql = (const short8*)(ws + WS_QL);
    f32x4 cv[2];
    cv[0] = (f32x4){0.f,0.f,0.f,0.f};
    cv[1] = (f32x4){0.f,0.f,0.f,0.f};
    #pragma unroll
    for (int kc = 0; kc < 2; kc++){
      int rb = wbase + ((16*kc + 4*q) ^ hswz);
      short8 bh = *(const short8*)(Uh + rb);
      short8 bl = *(const short8*)(Ul + rb);
      #pragma unroll
      for (int mt2 = 0; mt2 < 2; mt2++){
        int idx = (mt2*16 + l15)*8 + kc*4 + q;
        short8 qh = pqh[idx];
        short8 qlf = pql[idx];
        cv[mt2] = __builtin_amdgcn_mfma_f32_16x16x32_bf16(qh,  bh, cv[mt2], 0, 0, 0);
        cv[mt2] = __builtin_amdgcn_mfma_f32_16x16x32_bf16(qlf, bh, cv[mt2], 0, 0, 0);
        cv[mt2] = __builtin_amdgcn_mfma_f32_16x16x32_bf16(qh,  bl, cv[mt2], 0, 0, 0);
      }
    }
    float part = 0.f;
    #pragma unroll
    for (int mt2 = 0; mt2 < 2; mt2++){
      f32x4 cb = *(const f32x4*)(ws + WS_CB2 + mt2*16 + q*4);
      f32x4 p0 = *(const f32x4*)(zp0 + (long)(rowbase + l15)*96 + 64 + mt2*16 + q*4);
      f32x4 w2 = *(const f32x4*)(ws + WS_R2W + mt2*16 + q*4);
      #pragma unroll
      for (int rr = 0; rr < 4; rr++){
        float v = cv[mt2][rr] + cb[rr] + p0[rr];
        v = v > 0.0f ? v : 0.0f;
        part += w2[rr] * v;
      }
    }
    part += __shfl_xor(part, 16);
    part += __shfl_xor(part, 32);
    if (q == 0) out[rowbase + l15] = part + ws[WS_R2B];
  }
}

// ---------------------------------------------------------------------------
extern "C" void kernel_launch(void* const* d_in, const int* in_sizes, int n_in,
                              void* d_out, int out_size, void* d_ws, size_t ws_size,
                              hipStream_t stream){
  (void)in_sizes; (void)n_in; (void)out_size; (void)ws_size;
  float* ws = (float*)d_ws;

  k_detect<<<dim3(1), dim3(64), 0, stream>>>(d_in[0], d_in[1], ws);
  k0_convert<<<dim3(64), dim3(256), 0, stream>>>(
      d_in[2], d_in[3], d_in[4], d_in[5], d_in[6], d_in[7],
      d_in[8], d_in[9], d_in[10], d_in[11], d_in[12], d_in[13],
      d_in[14], d_in[15], ws);
  k1_encoder<<<dim3(BTOT/64), dim3(256), 0, stream>>>(d_in[0], ws, ws + WS_ZP0);
  k2_ode<<<dim3(BTOT/16), dim3(64), 0, stream>>>(ws, ws + WS_ZP0, (float*)d_out);
}